// Round 1
// baseline (2123.754 us; speedup 1.0000x reference)
//
#include <hip/hip_runtime.h>

#define HH 1024
#define WW 1024
#define RAD 8
#define EPSF 1e-4f
#define HWSZ (HH * WW)
#define NPL 41

__device__ __forceinline__ float wave_incl_scan(float v, int lane) {
#pragma unroll
  for (int off = 1; off < 64; off <<= 1) {
    float u = __shfl_up(v, off, 64);
    if (lane >= off) v += u;
  }
  return v;
}

__device__ __forceinline__ float wave_sum(float v) {
#pragma unroll
  for (int off = 1; off < 64; off <<= 1) v += __shfl_xor(v, off, 64);
  return v;
}

// K1: vertical box filter of 25 product channels -> ws planes 0..24
__global__ __launch_bounds__(256) void k_vbox25(const float* __restrict__ x,
                                                const float* __restrict__ g,
                                                float* __restrict__ ws, int b0) {
  const int col = blockIdx.x * 256 + threadIdx.x;
  const int y0 = blockIdx.y * 32;
  const int bi = blockIdx.z;
  const int b = b0 + bi;
  const float* gp0 = g + (size_t)(b * 3 + 0) * HWSZ;
  const float* gp1 = g + (size_t)(b * 3 + 1) * HWSZ;
  const float* gp2 = g + (size_t)(b * 3 + 2) * HWSZ;
  const float* sp0 = x + (size_t)(b * 4 + 0) * HWSZ;
  const float* sp1 = x + (size_t)(b * 4 + 1) * HWSZ;
  const float* sp2 = x + (size_t)(b * 4 + 2) * HWSZ;
  const float* sp3 = x + (size_t)(b * 4 + 3) * HWSZ;
  float* wsb = ws + (size_t)bi * NPL * HWSZ;

  float acc[25];
#pragma unroll
  for (int i = 0; i < 25; ++i) acc[i] = 0.f;

  auto vals = [&](int y, float* v) {
    const int off = y * WW + col;
    float g0 = gp0[off], g1 = gp1[off], g2 = gp2[off];
    float s0 = sp0[off], s1 = sp1[off], s2 = sp2[off], s3 = sp3[off];
    v[0] = g0; v[1] = g1; v[2] = g2;
    v[3] = s0; v[4] = s1; v[5] = s2; v[6] = s3;
    v[7] = g0 * s0; v[8] = g0 * s1; v[9] = g0 * s2; v[10] = g0 * s3;
    v[11] = g1 * s0; v[12] = g1 * s1; v[13] = g1 * s2; v[14] = g1 * s3;
    v[15] = g2 * s0; v[16] = g2 * s1; v[17] = g2 * s2; v[18] = g2 * s3;
    v[19] = g0 * g0; v[20] = g0 * g1; v[21] = g0 * g2;
    v[22] = g1 * g1; v[23] = g1 * g2; v[24] = g2 * g2;
  };

  for (int yy = y0 - RAD; yy <= y0 + RAD; ++yy) {
    if (yy >= 0 && yy < HH) {
      float v[25];
      vals(yy, v);
#pragma unroll
      for (int i = 0; i < 25; ++i) acc[i] += v[i];
    }
  }
  for (int y = y0; y < y0 + 32; ++y) {
    const size_t off = (size_t)y * WW + col;
#pragma unroll
    for (int i = 0; i < 25; ++i) wsb[(size_t)i * HWSZ + off] = acc[i];
    const int ye = y + RAD + 1;
    if (ye < HH) {
      float v[25];
      vals(ye, v);
#pragma unroll
      for (int i = 0; i < 25; ++i) acc[i] += v[i];
    }
    const int yl = y - RAD;
    if (yl >= 0) {
      float v[25];
      vals(yl, v);
#pragma unroll
      for (int i = 0; i < 25; ++i) acc[i] -= v[i];
    }
  }
}

// K2a: horizontal box of 25 stats (wave Delta-scan) + 3x3 solve -> a,b planes 25..40
__global__ __launch_bounds__(256) void k_hbox_pw(float* __restrict__ ws) {
  const int lane = threadIdx.x & 63;
  const int row = blockIdx.x * 4 + (threadIdx.x >> 6);
  const int bi = blockIdx.y;
  float* wsb = ws + (size_t)bi * NPL * HWSZ;
  const size_t roff = (size_t)row * WW;

  float run[25];
#pragma unroll
  for (int ch = 0; ch < 25; ++ch) {
    float t = (lane < 8) ? wsb[(size_t)ch * HWSZ + roff + lane] : 0.f;
    run[ch] = wave_sum(t);  // box value at col -1 (clipped window [0,7])
  }
  const int ny = min(row + RAD, HH - 1) - max(row - RAD, 0) + 1;
  const float invny = 1.0f / (float)ny;

  for (int s = 0; s < 16; ++s) {
    const int c = (s << 6) + lane;
    float hs[25];
#pragma unroll
    for (int ch = 0; ch < 25; ++ch) {
      const float* p = wsb + (size_t)ch * HWSZ + roff;
      float hi = (c + RAD < WW) ? p[c + RAD] : 0.f;
      float lo = (c >= RAD + 1) ? p[c - RAD - 1] : 0.f;
      float box = run[ch] + wave_incl_scan(hi - lo, lane);
      hs[ch] = box;
      run[ch] = __shfl(box, 63, 64);
    }
    const int nx = min(c + RAD, WW - 1) - max(c - RAD, 0) + 1;
    const float invN = invny / (float)nx;
    const float mI0 = hs[0] * invN, mI1 = hs[1] * invN, mI2 = hs[2] * invN;
    float mp[4];
#pragma unroll
    for (int cc = 0; cc < 4; ++cc) mp[cc] = hs[3 + cc] * invN;
    const float vrr = hs[19] * invN - mI0 * mI0 + EPSF;
    const float vrg = hs[20] * invN - mI0 * mI1;
    const float vrb = hs[21] * invN - mI0 * mI2;
    const float vgg = hs[22] * invN - mI1 * mI1 + EPSF;
    const float vgb = hs[23] * invN - mI1 * mI2;
    const float vbb = hs[24] * invN - mI2 * mI2 + EPSF;
    const float det = vrr * vgg * vbb + 2.f * vrg * vgb * vrb
                    - vrb * vgg * vrb - vrg * vrg * vbb - vrr * vgb * vgb;
    const float idet = 1.0f / det;
    const float i00 = (vgg * vbb - vgb * vgb) * idet;
    const float i01 = (vrb * vgb - vrg * vbb) * idet;
    const float i02 = (vrg * vgb - vrb * vgg) * idet;
    const float i11 = (vrr * vbb - vrb * vrb) * idet;
    const float i12 = (vrb * vrg - vrr * vgb) * idet;
    const float i22 = (vrr * vgg - vrg * vrg) * idet;
    const size_t o = roff + c;
#pragma unroll
    for (int cc = 0; cc < 4; ++cc) {
      const float cv0 = hs[7 + cc]  * invN - mI0 * mp[cc];
      const float cv1 = hs[11 + cc] * invN - mI1 * mp[cc];
      const float cv2 = hs[15 + cc] * invN - mI2 * mp[cc];
      const float a0 = cv0 * i00 + cv1 * i01 + cv2 * i02;
      const float a1 = cv0 * i01 + cv1 * i11 + cv2 * i12;
      const float a2 = cv0 * i02 + cv1 * i12 + cv2 * i22;
      const float bc = mp[cc] - (a0 * mI0 + a1 * mI1 + a2 * mI2);
      wsb[(size_t)(25 + cc) * HWSZ + o] = a0;
      wsb[(size_t)(29 + cc) * HWSZ + o] = a1;
      wsb[(size_t)(33 + cc) * HWSZ + o] = a2;
      wsb[(size_t)(37 + cc) * HWSZ + o] = bc;
    }
  }
}

// K2b: horizontal box of the 16 a/b channels (planes 25..40) -> planes 0..15
__global__ __launch_bounds__(256) void k_hbox_ab(float* __restrict__ ws) {
  const int lane = threadIdx.x & 63;
  const int row = blockIdx.x * 4 + (threadIdx.x >> 6);
  const int bi = blockIdx.y;
  float* wsb = ws + (size_t)bi * NPL * HWSZ;
  const size_t roff = (size_t)row * WW;
  float run[16];
#pragma unroll
  for (int ch = 0; ch < 16; ++ch) {
    float t = (lane < 8) ? wsb[(size_t)(25 + ch) * HWSZ + roff + lane] : 0.f;
    run[ch] = wave_sum(t);
  }
  for (int s = 0; s < 16; ++s) {
    const int c = (s << 6) + lane;
#pragma unroll
    for (int ch = 0; ch < 16; ++ch) {
      const float* p = wsb + (size_t)(25 + ch) * HWSZ + roff;
      float hi = (c + RAD < WW) ? p[c + RAD] : 0.f;
      float lo = (c >= RAD + 1) ? p[c - RAD - 1] : 0.f;
      float box = run[ch] + wave_incl_scan(hi - lo, lane);
      run[ch] = __shfl(box, 63, 64);
      wsb[(size_t)ch * HWSZ + roff + c] = box;
    }
  }
}

// K4: vertical box of boxed a/b (planes 0..15) + combine with guide -> q
__global__ __launch_bounds__(256) void k_vbox_comb(const float* __restrict__ ws_,
                                                   const float* __restrict__ g,
                                                   float* __restrict__ out, int b0) {
  const int col = blockIdx.x * 256 + threadIdx.x;
  const int y0 = blockIdx.y * 32;
  const int bi = blockIdx.z;
  const int b = b0 + bi;
  const float* wsb = ws_ + (size_t)bi * NPL * HWSZ;
  const float* gp0 = g + (size_t)(b * 3 + 0) * HWSZ;
  const float* gp1 = g + (size_t)(b * 3 + 1) * HWSZ;
  const float* gp2 = g + (size_t)(b * 3 + 2) * HWSZ;
  float* op0 = out + (size_t)(b * 4 + 0) * HWSZ;
  float* op1 = out + (size_t)(b * 4 + 1) * HWSZ;
  float* op2 = out + (size_t)(b * 4 + 2) * HWSZ;
  float* op3 = out + (size_t)(b * 4 + 3) * HWSZ;

  float acc[16];
#pragma unroll
  for (int i = 0; i < 16; ++i) acc[i] = 0.f;
  for (int yy = y0 - RAD; yy <= y0 + RAD; ++yy) {
    if (yy >= 0 && yy < HH) {
      const size_t off = (size_t)yy * WW + col;
#pragma unroll
      for (int i = 0; i < 16; ++i) acc[i] += wsb[(size_t)i * HWSZ + off];
    }
  }
  const int nx = min(col + RAD, WW - 1) - max(col - RAD, 0) + 1;
  const float invnx = 1.0f / (float)nx;
  for (int y = y0; y < y0 + 32; ++y) {
    const int ny = min(y + RAD, HH - 1) - max(y - RAD, 0) + 1;
    const float invN = invnx / (float)ny;
    const size_t off = (size_t)y * WW + col;
    const float g0 = gp0[off], g1 = gp1[off], g2 = gp2[off];
    op0[off] = (acc[0] * g0 + acc[4] * g1 + acc[8]  * g2 + acc[12]) * invN;
    op1[off] = (acc[1] * g0 + acc[5] * g1 + acc[9]  * g2 + acc[13]) * invN;
    op2[off] = (acc[2] * g0 + acc[6] * g1 + acc[10] * g2 + acc[14]) * invN;
    op3[off] = (acc[3] * g0 + acc[7] * g1 + acc[11] * g2 + acc[15]) * invN;
    const int ye = y + RAD + 1;
    if (ye < HH) {
      const size_t o2 = (size_t)ye * WW + col;
#pragma unroll
      for (int i = 0; i < 16; ++i) acc[i] += wsb[(size_t)i * HWSZ + o2];
    }
    const int yl = y - RAD;
    if (yl >= 0) {
      const size_t o2 = (size_t)yl * WW + col;
#pragma unroll
      for (int i = 0; i < 16; ++i) acc[i] -= wsb[(size_t)i * HWSZ + o2];
    }
  }
}

extern "C" void kernel_launch(void* const* d_in, const int* in_sizes, int n_in,
                              void* d_out, int out_size, void* d_ws, size_t ws_size,
                              hipStream_t stream) {
  const float* x = (const float*)d_in[0];   // (4,4,1024,1024) src p
  const float* g = (const float*)d_in[1];   // (4,3,1024,1024) guide
  float* out = (float*)d_out;
  float* ws = (float*)d_ws;
  const size_t perBatchBytes = (size_t)NPL * HWSZ * sizeof(float);  // 172 MB
  int nb = (int)(ws_size / perBatchBytes);
  if (nb < 1) nb = 1;
  if (nb > 4) nb = 4;
  for (int b0 = 0; b0 < 4; b0 += nb) {
    const int nbc = (4 - b0 < nb) ? (4 - b0) : nb;
    dim3 gv(WW / 256, HH / 32, nbc);
    dim3 gh(HH / 4, nbc);
    hipLaunchKernelGGL(k_vbox25, gv, dim3(256), 0, stream, x, g, ws, b0);
    hipLaunchKernelGGL(k_hbox_pw, gh, dim3(256), 0, stream, ws);
    hipLaunchKernelGGL(k_hbox_ab, gh, dim3(256), 0, stream, ws);
    hipLaunchKernelGGL(k_vbox_comb, gv, dim3(256), 0, stream, ws, g, out, b0);
  }
}

// Round 2
// 1127.080 us; speedup vs baseline: 1.8843x; 1.8843x over previous
//
#include <hip/hip_runtime.h>

#define HH 1024
#define WW 1024
#define RAD 8
#define EPSF 1e-4f
#define HWSZ (HH * WW)
#define NPL 41
#define EXT 320   // 256 output cols + 2*32 halo (covers +-8 window with wave alignment)

__device__ __forceinline__ float wave_incl_scan(float v, int lane) {
#pragma unroll
  for (int off = 1; off < 64; off <<= 1) {
    float u = __shfl_up(v, off, 64);
    if (lane >= off) v += u;
  }
  return v;
}

__device__ __forceinline__ float wave_sum(float v) {
#pragma unroll
  for (int off = 1; off < 64; off <<= 1) v += __shfl_xor(v, off, 64);
  return v;
}

// K1: vertical box filter of 25 product channels -> ws planes 0..24
// block = 64 threads (one 64-col strip), 8 output rows per block
__global__ __launch_bounds__(64) void k_vbox25(const float* __restrict__ x,
                                               const float* __restrict__ g,
                                               float* __restrict__ ws, int b0) {
  const int col = blockIdx.x * 64 + threadIdx.x;
  const int y0 = blockIdx.y * 8;
  const int bi = blockIdx.z;
  const int b = b0 + bi;
  const float* gp0 = g + (size_t)(b * 3 + 0) * HWSZ;
  const float* gp1 = g + (size_t)(b * 3 + 1) * HWSZ;
  const float* gp2 = g + (size_t)(b * 3 + 2) * HWSZ;
  const float* sp0 = x + (size_t)(b * 4 + 0) * HWSZ;
  const float* sp1 = x + (size_t)(b * 4 + 1) * HWSZ;
  const float* sp2 = x + (size_t)(b * 4 + 2) * HWSZ;
  const float* sp3 = x + (size_t)(b * 4 + 3) * HWSZ;
  float* wsb = ws + (size_t)bi * NPL * HWSZ;

  float acc[25];
#pragma unroll
  for (int i = 0; i < 25; ++i) acc[i] = 0.f;

  auto vals = [&](int y, float* v) {
    const int off = y * WW + col;
    float g0 = gp0[off], g1 = gp1[off], g2 = gp2[off];
    float s0 = sp0[off], s1 = sp1[off], s2 = sp2[off], s3 = sp3[off];
    v[0] = g0; v[1] = g1; v[2] = g2;
    v[3] = s0; v[4] = s1; v[5] = s2; v[6] = s3;
    v[7] = g0 * s0; v[8] = g0 * s1; v[9] = g0 * s2; v[10] = g0 * s3;
    v[11] = g1 * s0; v[12] = g1 * s1; v[13] = g1 * s2; v[14] = g1 * s3;
    v[15] = g2 * s0; v[16] = g2 * s1; v[17] = g2 * s2; v[18] = g2 * s3;
    v[19] = g0 * g0; v[20] = g0 * g1; v[21] = g0 * g2;
    v[22] = g1 * g1; v[23] = g1 * g2; v[24] = g2 * g2;
  };

  for (int yy = y0 - RAD; yy <= y0 + RAD; ++yy) {
    if (yy >= 0 && yy < HH) {
      float v[25];
      vals(yy, v);
#pragma unroll
      for (int i = 0; i < 25; ++i) acc[i] += v[i];
    }
  }
  for (int y = y0; y < y0 + 8; ++y) {
    const size_t off = (size_t)y * WW + col;
#pragma unroll
    for (int i = 0; i < 25; ++i) wsb[(size_t)i * HWSZ + off] = acc[i];
    const int ye = y + RAD + 1;
    if (ye < HH) {
      float v[25];
      vals(ye, v);
#pragma unroll
      for (int i = 0; i < 25; ++i) acc[i] += v[i];
    }
    const int yl = y - RAD;
    if (yl >= 0) {
      float v[25];
      vals(yl, v);
#pragma unroll
      for (int i = 0; i < 25; ++i) acc[i] -= v[i];
    }
  }
}

// K2 fused: hbox(25 stats) + per-pixel 3x3 solve -> a/b in LDS -> hbox(a/b)
// -> write boxed a/b to planes 25..40.
// block = 320 threads (5 waves). Tile: 256 output cols of one row.
// Phase A: 5 waves cover extended cols [c0-16, c0+304), each wave an
// independent 64-col segment: 17-tap init wave_sum + 64-wide delta scan.
__global__ __launch_bounds__(320) void k_hbox_fused(float* __restrict__ ws) {
  const int lane = threadIdx.x & 63;
  const int w = threadIdx.x >> 6;
  const int row = blockIdx.y;
  const int c0 = blockIdx.x * 256;
  const int bi = blockIdx.z;
  float* wsb = ws + (size_t)bi * NPL * HWSZ;
  const size_t roff = (size_t)row * WW;

  __shared__ float ab[16][EXT];

  // ---- Phase A: stats hbox + pointwise solve at extended cols ----
  {
    const int sA = c0 - 16 + 64 * w;    // segment base (ext coords rel0 = 64*w)
    const int cext = sA + lane;
    float hs[25];
#pragma unroll
    for (int ch = 0; ch < 25; ++ch) {
      const float* p = wsb + (size_t)ch * HWSZ + roff;
      const int ih = cext + RAD;
      const int il = cext - RAD - 1;
      const int ii = sA - RAD - 1 + lane;
      float hi = (ih >= 0 && ih < WW) ? p[ih] : 0.f;
      float lo = (il >= 0 && il < WW) ? p[il] : 0.f;
      float iv = (lane < 2 * RAD + 1 && ii >= 0 && ii < WW) ? p[ii] : 0.f;
      float init = wave_sum(iv);                      // box at col sA-1
      hs[ch] = init + wave_incl_scan(hi - lo, lane);  // box at col cext
    }
    const int ny = min(row + RAD, HH - 1) - max(row - RAD, 0) + 1;
    const int nx = min(cext + RAD, WW - 1) - max(cext - RAD, 0) + 1;
    const float invN = 1.0f / ((float)ny * (float)nx);
    const bool valid = (cext >= 0 && cext < WW);
    const float mI0 = hs[0] * invN, mI1 = hs[1] * invN, mI2 = hs[2] * invN;
    float mp[4];
#pragma unroll
    for (int cc = 0; cc < 4; ++cc) mp[cc] = hs[3 + cc] * invN;
    const float vrr = hs[19] * invN - mI0 * mI0 + EPSF;
    const float vrg = hs[20] * invN - mI0 * mI1;
    const float vrb = hs[21] * invN - mI0 * mI2;
    const float vgg = hs[22] * invN - mI1 * mI1 + EPSF;
    const float vgb = hs[23] * invN - mI1 * mI2;
    const float vbb = hs[24] * invN - mI2 * mI2 + EPSF;
    const float det = vrr * vgg * vbb + 2.f * vrg * vgb * vrb
                    - vrb * vgg * vrb - vrg * vrg * vbb - vrr * vgb * vgb;
    const float idet = 1.0f / det;
    const float i00 = (vgg * vbb - vgb * vgb) * idet;
    const float i01 = (vrb * vgb - vrg * vbb) * idet;
    const float i02 = (vrg * vgb - vrb * vgg) * idet;
    const float i11 = (vrr * vbb - vrb * vrb) * idet;
    const float i12 = (vrb * vrg - vrr * vgb) * idet;
    const float i22 = (vrr * vgg - vrg * vrg) * idet;
    const int rel = 64 * w + lane;
#pragma unroll
    for (int cc = 0; cc < 4; ++cc) {
      const float cv0 = hs[7 + cc]  * invN - mI0 * mp[cc];
      const float cv1 = hs[11 + cc] * invN - mI1 * mp[cc];
      const float cv2 = hs[15 + cc] * invN - mI2 * mp[cc];
      const float a0 = cv0 * i00 + cv1 * i01 + cv2 * i02;
      const float a1 = cv0 * i01 + cv1 * i11 + cv2 * i12;
      const float a2 = cv0 * i02 + cv1 * i12 + cv2 * i22;
      const float bc = mp[cc] - (a0 * mI0 + a1 * mI1 + a2 * mI2);
      ab[cc][rel]      = valid ? a0 : 0.f;
      ab[4 + cc][rel]  = valid ? a1 : 0.f;
      ab[8 + cc][rel]  = valid ? a2 : 0.f;
      ab[12 + cc][rel] = valid ? bc : 0.f;
    }
  }
  __syncthreads();

  // ---- Phase B: hbox over a/b from LDS, 4 waves x 64 output cols ----
  if (w < 4) {
    const int oc = c0 + 64 * w + lane;   // output col (< 1024 always)
    const int rel = 16 + 64 * w + lane;  // ext coords
    const int rel0 = 16 + 64 * w;        // segment base in ext coords
#pragma unroll
    for (int ch = 0; ch < 16; ++ch) {
      float hi = ab[ch][rel + RAD];
      float lo = ab[ch][rel - RAD - 1];
      float iv = (lane < 2 * RAD + 1) ? ab[ch][rel0 - RAD - 1 + lane] : 0.f;
      float init = wave_sum(iv);
      float box = init + wave_incl_scan(hi - lo, lane);
      wsb[(size_t)(25 + ch) * HWSZ + roff + oc] = box;
    }
  }
}

// K3: vertical box of boxed a/b (planes 25..40) + combine with guide -> q
// block = 64 threads, 16 output rows per block
__global__ __launch_bounds__(64) void k_vbox_comb(const float* __restrict__ ws_,
                                                  const float* __restrict__ g,
                                                  float* __restrict__ out, int b0) {
  const int col = blockIdx.x * 64 + threadIdx.x;
  const int y0 = blockIdx.y * 16;
  const int bi = blockIdx.z;
  const int b = b0 + bi;
  const float* wsb = ws_ + (size_t)bi * NPL * HWSZ + (size_t)25 * HWSZ;
  const float* gp0 = g + (size_t)(b * 3 + 0) * HWSZ;
  const float* gp1 = g + (size_t)(b * 3 + 1) * HWSZ;
  const float* gp2 = g + (size_t)(b * 3 + 2) * HWSZ;
  float* op0 = out + (size_t)(b * 4 + 0) * HWSZ;
  float* op1 = out + (size_t)(b * 4 + 1) * HWSZ;
  float* op2 = out + (size_t)(b * 4 + 2) * HWSZ;
  float* op3 = out + (size_t)(b * 4 + 3) * HWSZ;

  float acc[16];
#pragma unroll
  for (int i = 0; i < 16; ++i) acc[i] = 0.f;
  for (int yy = y0 - RAD; yy <= y0 + RAD; ++yy) {
    if (yy >= 0 && yy < HH) {
      const size_t off = (size_t)yy * WW + col;
#pragma unroll
      for (int i = 0; i < 16; ++i) acc[i] += wsb[(size_t)i * HWSZ + off];
    }
  }
  const int nx = min(col + RAD, WW - 1) - max(col - RAD, 0) + 1;
  const float invnx = 1.0f / (float)nx;
  for (int y = y0; y < y0 + 16; ++y) {
    const int ny = min(y + RAD, HH - 1) - max(y - RAD, 0) + 1;
    const float invN = invnx / (float)ny;
    const size_t off = (size_t)y * WW + col;
    const float g0 = gp0[off], g1 = gp1[off], g2 = gp2[off];
    op0[off] = (acc[0] * g0 + acc[4] * g1 + acc[8]  * g2 + acc[12]) * invN;
    op1[off] = (acc[1] * g0 + acc[5] * g1 + acc[9]  * g2 + acc[13]) * invN;
    op2[off] = (acc[2] * g0 + acc[6] * g1 + acc[10] * g2 + acc[14]) * invN;
    op3[off] = (acc[3] * g0 + acc[7] * g1 + acc[11] * g2 + acc[15]) * invN;
    const int ye = y + RAD + 1;
    if (ye < HH) {
      const size_t o2 = (size_t)ye * WW + col;
#pragma unroll
      for (int i = 0; i < 16; ++i) acc[i] += wsb[(size_t)i * HWSZ + o2];
    }
    const int yl = y - RAD;
    if (yl >= 0) {
      const size_t o2 = (size_t)yl * WW + col;
#pragma unroll
      for (int i = 0; i < 16; ++i) acc[i] -= wsb[(size_t)i * HWSZ + o2];
    }
  }
}

extern "C" void kernel_launch(void* const* d_in, const int* in_sizes, int n_in,
                              void* d_out, int out_size, void* d_ws, size_t ws_size,
                              hipStream_t stream) {
  const float* x = (const float*)d_in[0];   // (4,4,1024,1024) src p
  const float* g = (const float*)d_in[1];   // (4,3,1024,1024) guide
  float* out = (float*)d_out;
  float* ws = (float*)d_ws;
  const size_t perBatchBytes = (size_t)NPL * HWSZ * sizeof(float);  // 172 MB
  int nb = (int)(ws_size / perBatchBytes);
  if (nb < 1) nb = 1;
  if (nb > 4) nb = 4;
  for (int b0 = 0; b0 < 4; b0 += nb) {
    const int nbc = (4 - b0 < nb) ? (4 - b0) : nb;
    dim3 g1(WW / 64, HH / 8, nbc);
    dim3 g2(WW / 256, HH, nbc);
    dim3 g3(WW / 64, HH / 16, nbc);
    hipLaunchKernelGGL(k_vbox25, g1, dim3(64), 0, stream, x, g, ws, b0);
    hipLaunchKernelGGL(k_hbox_fused, g2, dim3(320), 0, stream, ws);
    hipLaunchKernelGGL(k_vbox_comb, g3, dim3(64), 0, stream, ws, g, out, b0);
  }
}

// Round 4
// 770.341 us; speedup vs baseline: 2.7569x; 1.4631x over previous
//
#include <hip/hip_runtime.h>

#define HH 1024
#define WW 1024
#define RAD 8
#define EPSF 1e-4f
#define HWSZ (HH * WW)
#define NPL 41
#define T2 216   // output cols per wave in k_hbox_solve
#define NTL 5    // tiles per row (216*5 = 1080 >= 1024)
#define V1R 4    // rows per block, k_vbox25
#define V3R 4    // rows per block, k_vbox_comb

__device__ __forceinline__ float wave_incl_scan(float v, int lane) {
#pragma unroll
  for (int off = 1; off < 64; off <<= 1) {
    float u = __shfl_up(v, off, 64);
    if (lane >= off) v += u;
  }
  return v;
}

// ---------------- K1: vertical box of 25 product channels -> planes 0..24
__global__ __launch_bounds__(64) void k_vbox25(const float* __restrict__ x,
                                               const float* __restrict__ g,
                                               float* __restrict__ ws, int b0) {
  const int c0 = blockIdx.x * 128 + threadIdx.x * 2;
  const int y0 = blockIdx.y * V1R;
  const int b = b0 + blockIdx.z;
  const float* gp0 = g + (size_t)(b * 3 + 0) * HWSZ;
  const float* gp1 = g + (size_t)(b * 3 + 1) * HWSZ;
  const float* gp2 = g + (size_t)(b * 3 + 2) * HWSZ;
  const float* sp0 = x + (size_t)(b * 4 + 0) * HWSZ;
  const float* sp1 = x + (size_t)(b * 4 + 1) * HWSZ;
  const float* sp2 = x + (size_t)(b * 4 + 2) * HWSZ;
  const float* sp3 = x + (size_t)(b * 4 + 3) * HWSZ;
  float* wsb = ws + (size_t)blockIdx.z * NPL * HWSZ;

  float acc[25][2];
#pragma unroll
  for (int i = 0; i < 25; ++i) { acc[i][0] = 0.f; acc[i][1] = 0.f; }

  auto row_op = [&](int y, bool add) {
    const int off = y * WW + c0;
    const float2 G0 = *(const float2*)(gp0 + off);
    const float2 G1 = *(const float2*)(gp1 + off);
    const float2 G2 = *(const float2*)(gp2 + off);
    const float2 S0 = *(const float2*)(sp0 + off);
    const float2 S1 = *(const float2*)(sp1 + off);
    const float2 S2 = *(const float2*)(sp2 + off);
    const float2 S3 = *(const float2*)(sp3 + off);
    const float gg0[2] = {G0.x, G0.y}, gg1[2] = {G1.x, G1.y}, gg2[2] = {G2.x, G2.y};
    const float ss0[2] = {S0.x, S0.y}, ss1[2] = {S1.x, S1.y},
                ss2[2] = {S2.x, S2.y}, ss3[2] = {S3.x, S3.y};
#pragma unroll
    for (int k = 0; k < 2; ++k) {
      float o[25];
      o[0] = gg0[k]; o[1] = gg1[k]; o[2] = gg2[k];
      o[3] = ss0[k]; o[4] = ss1[k]; o[5] = ss2[k]; o[6] = ss3[k];
      o[7]  = gg0[k] * ss0[k]; o[8]  = gg0[k] * ss1[k];
      o[9]  = gg0[k] * ss2[k]; o[10] = gg0[k] * ss3[k];
      o[11] = gg1[k] * ss0[k]; o[12] = gg1[k] * ss1[k];
      o[13] = gg1[k] * ss2[k]; o[14] = gg1[k] * ss3[k];
      o[15] = gg2[k] * ss0[k]; o[16] = gg2[k] * ss1[k];
      o[17] = gg2[k] * ss2[k]; o[18] = gg2[k] * ss3[k];
      o[19] = gg0[k] * gg0[k]; o[20] = gg0[k] * gg1[k]; o[21] = gg0[k] * gg2[k];
      o[22] = gg1[k] * gg1[k]; o[23] = gg1[k] * gg2[k]; o[24] = gg2[k] * gg2[k];
      if (add) {
#pragma unroll
        for (int i = 0; i < 25; ++i) acc[i][k] += o[i];
      } else {
#pragma unroll
        for (int i = 0; i < 25; ++i) acc[i][k] -= o[i];
      }
    }
  };

  for (int yy = y0 - RAD; yy <= y0 + RAD; ++yy)
    if (yy >= 0 && yy < HH) row_op(yy, true);

  for (int y = y0; y < y0 + V1R; ++y) {
    const size_t off = (size_t)y * WW + c0;
#pragma unroll
    for (int i = 0; i < 25; ++i)
      *(float2*)(wsb + (size_t)i * HWSZ + off) = make_float2(acc[i][0], acc[i][1]);
    const int ye = y + RAD + 1;
    if (ye < HH) row_op(ye, true);
    const int yl = y - RAD;
    if (yl >= 0) row_op(yl, false);
  }
}

// ---------------- K2: hbox(stats) + 3x3 solve + hbox(a/b), register-resident
// One wave per (row, tile): loads span of 256 cols [E, E+256), E = F-20;
// outputs boxed a/b at cols [F, F+216). Prefix-difference trick: no init,
// no carry, no LDS, no syncs.
__global__ __launch_bounds__(256) void k_hbox_solve(float* __restrict__ ws) {
  const int lane = threadIdx.x & 63;
  const int w = threadIdx.x >> 6;
  const int bi = blockIdx.y;
  const int gw = blockIdx.x * 4 + w;          // 0 .. 5119
  const int row = gw / NTL;
  const int tix = gw - row * NTL;
  float* wsb = ws + (size_t)bi * NPL * HWSZ;
  const size_t roff = (size_t)row * WW;
  const int F = tix * T2;
  const int E = F - 20;
  const int relmax = (WW - 1) - E;            // rel index of col W-1 (==3 mod 4)
  const int col0 = E + 4 * lane;
  const bool ldok = (col0 >= 0) && (col0 < WW);

  const int ny = min(row + RAD, HH - 1) - max(row - RAD, 0) + 1;
  const float invny = 1.0f / (float)ny;
  const int cbase = E + 12 + 4 * lane;        // this thread's a/b col base
  float invN[4];
#pragma unroll
  for (int j = 0; j < 4; ++j) {
    const int c = cbase + j;
    const int nx = min(c + RAD, WW - 1) - max(c - RAD, 0) + 1;
    invN[j] = invny / (float)nx;
  }
  const bool abok = (lane <= 58) && (cbase >= 0) && (cbase < WW);

  // horizontal box of plane ch at this thread's 4 a/b cols (unnormalized)
  auto hboxA = [&](int ch, float out[4]) {
    const float* p = wsb + (size_t)ch * HWSZ + roff;
    float4 v;
    if (ldok) v = *(const float4*)(p + col0);
    else v = make_float4(0.f, 0.f, 0.f, 0.f);
    const float s1 = v.x + v.y, s2 = s1 + v.z, ts = s2 + v.w;
    const float incl = wave_incl_scan(ts, lane);
    const float base = incl - ts;
    const float P0 = base + v.x, P1 = base + s1, P2 = base + s2, P3 = incl;
    const float PW = __shfl(P3, min(relmax >> 2, 63));
    const float hh[4] = {__shfl(P0, lane + 5), __shfl(P1, lane + 5),
                         __shfl(P2, lane + 5), __shfl(P3, lane + 5)};
    const float ll[4] = {P3, __shfl(P0, lane + 1), __shfl(P1, lane + 1),
                         __shfl(P2, lane + 1)};
    const int r0 = 4 * lane + 12;
#pragma unroll
    for (int j = 0; j < 4; ++j) {
      const float hi = (r0 + j + 8 <= relmax) ? hh[j] : PW;
      const float lo = (E + r0 + j >= 9) ? ll[j] : 0.f;
      out[j] = hi - lo;
    }
  };

  // guide means
  float mI[3][4];
#pragma unroll
  for (int k = 0; k < 3; ++k) {
    float t[4];
    hboxA(k, t);
#pragma unroll
    for (int j = 0; j < 4; ++j) mI[k][j] = t[j] * invN[j];
  }
  // covariance of guide -> inverse (symmetric 3x3)
  float inv[6][4];
  {
    float v19[4], v20[4], v21[4], v22[4], v23[4], v24[4];
    hboxA(19, v19); hboxA(20, v20); hboxA(21, v21);
    hboxA(22, v22); hboxA(23, v23); hboxA(24, v24);
#pragma unroll
    for (int j = 0; j < 4; ++j) {
      const float rr = v19[j] * invN[j] - mI[0][j] * mI[0][j] + EPSF;
      const float rg = v20[j] * invN[j] - mI[0][j] * mI[1][j];
      const float rb = v21[j] * invN[j] - mI[0][j] * mI[2][j];
      const float gg = v22[j] * invN[j] - mI[1][j] * mI[1][j] + EPSF;
      const float gb = v23[j] * invN[j] - mI[1][j] * mI[2][j];
      const float bb = v24[j] * invN[j] - mI[2][j] * mI[2][j] + EPSF;
      const float det = rr * gg * bb + 2.f * rg * gb * rb
                      - rb * gg * rb - rg * rg * bb - rr * gb * gb;
      const float idet = 1.0f / det;
      inv[0][j] = (gg * bb - gb * gb) * idet;
      inv[1][j] = (rb * gb - rg * bb) * idet;
      inv[2][j] = (rg * gb - rb * gg) * idet;
      inv[3][j] = (rr * bb - rb * rb) * idet;
      inv[4][j] = (rb * rg - rr * gb) * idet;
      inv[5][j] = (rr * gg - rg * rg) * idet;
    }
  }
  // per-src-channel solve -> a0,a1,a2,b
  float ab[16][4];
#pragma unroll
  for (int cc = 0; cc < 4; ++cc) {
    float mp[4], q0[4], q1[4], q2[4];
    hboxA(3 + cc, mp);
    hboxA(7 + cc, q0);
    hboxA(11 + cc, q1);
    hboxA(15 + cc, q2);
#pragma unroll
    for (int j = 0; j < 4; ++j) {
      const float m = mp[j] * invN[j];
      const float c0v = q0[j] * invN[j] - mI[0][j] * m;
      const float c1v = q1[j] * invN[j] - mI[1][j] * m;
      const float c2v = q2[j] * invN[j] - mI[2][j] * m;
      const float a0 = c0v * inv[0][j] + c1v * inv[1][j] + c2v * inv[2][j];
      const float a1 = c0v * inv[1][j] + c1v * inv[3][j] + c2v * inv[4][j];
      const float a2 = c0v * inv[2][j] + c1v * inv[4][j] + c2v * inv[5][j];
      const float bv = m - (a0 * mI[0][j] + a1 * mI[1][j] + a2 * mI[2][j]);
      ab[cc][j]      = abok ? a0 : 0.f;
      ab[4 + cc][j]  = abok ? a1 : 0.f;
      ab[8 + cc][j]  = abok ? a2 : 0.f;
      ab[12 + cc][j] = abok ? bv : 0.f;
    }
  }
  // phase B: hbox over a/b straight from registers -> planes 25..40
  const int qmax = relmax - 12;
  const int nstore = min(54, (WW - F) >> 2);
  const bool stok = lane < nstore;
  const size_t obase = roff + F + 4 * lane;
#pragma unroll
  for (int m = 0; m < 16; ++m) {
    const float x0 = ab[m][0], x1 = ab[m][1], x2 = ab[m][2], x3 = ab[m][3];
    const float s1 = x0 + x1, s2 = s1 + x2, ts = s2 + x3;
    const float incl = wave_incl_scan(ts, lane);
    const float base = incl - ts;
    const float Q0 = base + x0, Q1 = base + s1, Q2 = base + s2, Q3 = incl;
    const float PW2 = __shfl(Q3, min(qmax >> 2, 63));
    const float hh[4] = {__shfl(Q0, lane + 4), __shfl(Q1, lane + 4),
                         __shfl(Q2, lane + 4), __shfl(Q3, lane + 4)};
    const float lm1 = __shfl(Q3, lane - 1);
    const float ll[4] = {lm1, Q0, Q1, Q2};
    const int qf0 = 8 + 4 * lane;
    float o[4];
#pragma unroll
    for (int j = 0; j < 4; ++j) {
      const float hi = (qf0 + j + 8 <= qmax) ? hh[j] : PW2;
      const float lo = (qf0 + j >= 9) ? ll[j] : 0.f;
      o[j] = hi - lo;
    }
    if (stok)
      *(float4*)(wsb + (size_t)(25 + m) * HWSZ + obase) =
          make_float4(o[0], o[1], o[2], o[3]);
  }
}

// ---------------- K3: vertical box of boxed a/b + combine with guide -> q
__global__ __launch_bounds__(64) void k_vbox_comb(const float* __restrict__ ws_,
                                                  const float* __restrict__ g,
                                                  float* __restrict__ out, int b0) {
  const int c0 = blockIdx.x * 128 + threadIdx.x * 2;
  const int y0 = blockIdx.y * V3R;
  const int b = b0 + blockIdx.z;
  const float* wsb = ws_ + (size_t)blockIdx.z * NPL * HWSZ + (size_t)25 * HWSZ;
  const float* gp0 = g + (size_t)(b * 3 + 0) * HWSZ;
  const float* gp1 = g + (size_t)(b * 3 + 1) * HWSZ;
  const float* gp2 = g + (size_t)(b * 3 + 2) * HWSZ;
  float* op0 = out + (size_t)(b * 4 + 0) * HWSZ;
  float* op1 = out + (size_t)(b * 4 + 1) * HWSZ;
  float* op2 = out + (size_t)(b * 4 + 2) * HWSZ;
  float* op3 = out + (size_t)(b * 4 + 3) * HWSZ;

  float acc[16][2];
#pragma unroll
  for (int i = 0; i < 16; ++i) { acc[i][0] = 0.f; acc[i][1] = 0.f; }

  auto row_op = [&](int y, bool add) {
    const int off = y * WW + c0;
#pragma unroll
    for (int i = 0; i < 16; ++i) {
      const float2 v = *(const float2*)(wsb + (size_t)i * HWSZ + off);
      if (add) { acc[i][0] += v.x; acc[i][1] += v.y; }
      else     { acc[i][0] -= v.x; acc[i][1] -= v.y; }
    }
  };

  for (int yy = y0 - RAD; yy <= y0 + RAD; ++yy)
    if (yy >= 0 && yy < HH) row_op(yy, true);

  float invnx[2];
#pragma unroll
  for (int k = 0; k < 2; ++k) {
    const int c = c0 + k;
    const int nx = min(c + RAD, WW - 1) - max(c - RAD, 0) + 1;
    invnx[k] = 1.0f / (float)nx;
  }

  for (int y = y0; y < y0 + V3R; ++y) {
    const int ny = min(y + RAD, HH - 1) - max(y - RAD, 0) + 1;
    const float invny = 1.0f / (float)ny;
    const size_t off = (size_t)y * WW + c0;
    const float2 G0 = *(const float2*)(gp0 + off);
    const float2 G1 = *(const float2*)(gp1 + off);
    const float2 G2 = *(const float2*)(gp2 + off);
    const float gk0[2] = {G0.x, G0.y}, gk1[2] = {G1.x, G1.y}, gk2[2] = {G2.x, G2.y};
    float o0[2], o1[2], o2[2], o3[2];
#pragma unroll
    for (int k = 0; k < 2; ++k) {
      const float invN = invnx[k] * invny;
      o0[k] = (acc[0][k] * gk0[k] + acc[4][k] * gk1[k] + acc[8][k]  * gk2[k] + acc[12][k]) * invN;
      o1[k] = (acc[1][k] * gk0[k] + acc[5][k] * gk1[k] + acc[9][k]  * gk2[k] + acc[13][k]) * invN;
      o2[k] = (acc[2][k] * gk0[k] + acc[6][k] * gk1[k] + acc[10][k] * gk2[k] + acc[14][k]) * invN;
      o3[k] = (acc[3][k] * gk0[k] + acc[7][k] * gk1[k] + acc[11][k] * gk2[k] + acc[15][k]) * invN;
    }
    *(float2*)(op0 + off) = make_float2(o0[0], o0[1]);
    *(float2*)(op1 + off) = make_float2(o1[0], o1[1]);
    *(float2*)(op2 + off) = make_float2(o2[0], o2[1]);
    *(float2*)(op3 + off) = make_float2(o3[0], o3[1]);
    const int ye = y + RAD + 1;
    if (ye < HH) row_op(ye, true);
    const int yl = y - RAD;
    if (yl >= 0) row_op(yl, false);
  }
}

extern "C" void kernel_launch(void* const* d_in, const int* in_sizes, int n_in,
                              void* d_out, int out_size, void* d_ws, size_t ws_size,
                              hipStream_t stream) {
  const float* x = (const float*)d_in[0];   // (4,4,1024,1024) src p
  const float* g = (const float*)d_in[1];   // (4,3,1024,1024) guide
  float* out = (float*)d_out;
  float* ws = (float*)d_ws;
  const size_t perBatchBytes = (size_t)NPL * HWSZ * sizeof(float);  // 172 MB
  int nb = (int)(ws_size / perBatchBytes);
  if (nb < 1) nb = 1;
  if (nb > 4) nb = 4;
  for (int b0 = 0; b0 < 4; b0 += nb) {
    const int nbc = (4 - b0 < nb) ? (4 - b0) : nb;
    dim3 g1(WW / 128, HH / V1R, nbc);
    dim3 g2(HH * NTL / 4, nbc);
    dim3 g3(WW / 128, HH / V3R, nbc);
    hipLaunchKernelGGL(k_vbox25, g1, dim3(64), 0, stream, x, g, ws, b0);
    hipLaunchKernelGGL(k_hbox_solve, g2, dim3(256), 0, stream, ws);
    hipLaunchKernelGGL(k_vbox_comb, g3, dim3(64), 0, stream, ws, g, out, b0);
  }
}

// Round 5
// 661.259 us; speedup vs baseline: 3.2117x; 1.1650x over previous
//
#include <hip/hip_runtime.h>

#define HH 1024
#define WW 1024
#define RAD 8
#define EPSF 1e-4f
#define HWSZ (HH * WW)
#define NPL 41
#define T2 216   // output cols per wave in k_hbox_solve
#define NTL 5    // tiles per row (216*5 = 1080 >= 1024)
#define V1R 8    // rows per block, k_vbox25
#define V3R 8    // rows per block, k_vbox_comb

// Inclusive wave64 prefix scan via DPP (VALU-only, no LDS pipe).
// row_shr:1/2/4/8 within 16-lane rows, then row_bcast:15 (rows 1,3),
// row_bcast:31 (rows 2,3). old=0 => invalid/masked lanes contribute 0.
__device__ __forceinline__ float wave_incl_scan(float v) {
  int t;
  t = __builtin_amdgcn_update_dpp(0, __float_as_int(v), 0x111, 0xf, 0xf, false);
  v += __int_as_float(t);
  t = __builtin_amdgcn_update_dpp(0, __float_as_int(v), 0x112, 0xf, 0xf, false);
  v += __int_as_float(t);
  t = __builtin_amdgcn_update_dpp(0, __float_as_int(v), 0x114, 0xf, 0xf, false);
  v += __int_as_float(t);
  t = __builtin_amdgcn_update_dpp(0, __float_as_int(v), 0x118, 0xf, 0xf, false);
  v += __int_as_float(t);
  t = __builtin_amdgcn_update_dpp(0, __float_as_int(v), 0x142, 0xa, 0xf, false);
  v += __int_as_float(t);
  t = __builtin_amdgcn_update_dpp(0, __float_as_int(v), 0x143, 0xc, 0xf, false);
  v += __int_as_float(t);
  return v;
}

// ---------------- K1: vertical box of 25 product channels -> planes 0..24
__global__ __launch_bounds__(64) void k_vbox25(const float* __restrict__ x,
                                               const float* __restrict__ g,
                                               float* __restrict__ ws, int b0) {
  const int c0 = blockIdx.x * 128 + threadIdx.x * 2;
  const int y0 = blockIdx.y * V1R;
  const int b = b0 + blockIdx.z;
  const float* gp0 = g + (size_t)(b * 3 + 0) * HWSZ;
  const float* gp1 = g + (size_t)(b * 3 + 1) * HWSZ;
  const float* gp2 = g + (size_t)(b * 3 + 2) * HWSZ;
  const float* sp0 = x + (size_t)(b * 4 + 0) * HWSZ;
  const float* sp1 = x + (size_t)(b * 4 + 1) * HWSZ;
  const float* sp2 = x + (size_t)(b * 4 + 2) * HWSZ;
  const float* sp3 = x + (size_t)(b * 4 + 3) * HWSZ;
  float* wsb = ws + (size_t)blockIdx.z * NPL * HWSZ;

  float acc[25][2];
#pragma unroll
  for (int i = 0; i < 25; ++i) { acc[i][0] = 0.f; acc[i][1] = 0.f; }

  auto row_op = [&](int y, bool add) {
    const int off = y * WW + c0;
    const float2 G0 = *(const float2*)(gp0 + off);
    const float2 G1 = *(const float2*)(gp1 + off);
    const float2 G2 = *(const float2*)(gp2 + off);
    const float2 S0 = *(const float2*)(sp0 + off);
    const float2 S1 = *(const float2*)(sp1 + off);
    const float2 S2 = *(const float2*)(sp2 + off);
    const float2 S3 = *(const float2*)(sp3 + off);
    const float gg0[2] = {G0.x, G0.y}, gg1[2] = {G1.x, G1.y}, gg2[2] = {G2.x, G2.y};
    const float ss0[2] = {S0.x, S0.y}, ss1[2] = {S1.x, S1.y},
                ss2[2] = {S2.x, S2.y}, ss3[2] = {S3.x, S3.y};
#pragma unroll
    for (int k = 0; k < 2; ++k) {
      float o[25];
      o[0] = gg0[k]; o[1] = gg1[k]; o[2] = gg2[k];
      o[3] = ss0[k]; o[4] = ss1[k]; o[5] = ss2[k]; o[6] = ss3[k];
      o[7]  = gg0[k] * ss0[k]; o[8]  = gg0[k] * ss1[k];
      o[9]  = gg0[k] * ss2[k]; o[10] = gg0[k] * ss3[k];
      o[11] = gg1[k] * ss0[k]; o[12] = gg1[k] * ss1[k];
      o[13] = gg1[k] * ss2[k]; o[14] = gg1[k] * ss3[k];
      o[15] = gg2[k] * ss0[k]; o[16] = gg2[k] * ss1[k];
      o[17] = gg2[k] * ss2[k]; o[18] = gg2[k] * ss3[k];
      o[19] = gg0[k] * gg0[k]; o[20] = gg0[k] * gg1[k]; o[21] = gg0[k] * gg2[k];
      o[22] = gg1[k] * gg1[k]; o[23] = gg1[k] * gg2[k]; o[24] = gg2[k] * gg2[k];
      if (add) {
#pragma unroll
        for (int i = 0; i < 25; ++i) acc[i][k] += o[i];
      } else {
#pragma unroll
        for (int i = 0; i < 25; ++i) acc[i][k] -= o[i];
      }
    }
  };

  for (int yy = y0 - RAD; yy <= y0 + RAD; ++yy)
    if (yy >= 0 && yy < HH) row_op(yy, true);

  for (int y = y0; y < y0 + V1R; ++y) {
    const size_t off = (size_t)y * WW + c0;
#pragma unroll
    for (int i = 0; i < 25; ++i)
      *(float2*)(wsb + (size_t)i * HWSZ + off) = make_float2(acc[i][0], acc[i][1]);
    const int ye = y + RAD + 1;
    if (ye < HH) row_op(ye, true);
    const int yl = y - RAD;
    if (yl >= 0) row_op(yl, false);
  }
}

// ---------------- K2: hbox(stats) + 3x3 solve + hbox(a/b), register-resident
// One wave per (row, tile): loads span of 256 cols [E, E+256), E = F-20;
// outputs boxed a/b at cols [F, F+216). Prefix-difference trick: no init,
// no carry, no LDS, no syncs.
__global__ __launch_bounds__(256) void k_hbox_solve(float* __restrict__ ws) {
  const int lane = threadIdx.x & 63;
  const int w = threadIdx.x >> 6;
  const int bi = blockIdx.y;
  const int gw = blockIdx.x * 4 + w;          // 0 .. 5119
  const int row = gw / NTL;
  const int tix = gw - row * NTL;
  float* wsb = ws + (size_t)bi * NPL * HWSZ;
  const size_t roff = (size_t)row * WW;
  const int F = tix * T2;
  const int E = F - 20;
  const int relmax = (WW - 1) - E;            // rel index of col W-1 (==3 mod 4)
  const int col0 = E + 4 * lane;
  const bool ldok = (col0 >= 0) && (col0 < WW);

  const int ny = min(row + RAD, HH - 1) - max(row - RAD, 0) + 1;
  const float invny = 1.0f / (float)ny;
  const int cbase = E + 12 + 4 * lane;        // this thread's a/b col base
  float invN[4];
#pragma unroll
  for (int j = 0; j < 4; ++j) {
    const int c = cbase + j;
    const int nx = min(c + RAD, WW - 1) - max(c - RAD, 0) + 1;
    invN[j] = invny / (float)nx;
  }
  const bool abok = (lane <= 58) && (cbase >= 0) && (cbase < WW);

  // horizontal box of plane ch at this thread's 4 a/b cols (unnormalized)
  auto hboxA = [&](int ch, float out[4]) {
    const float* p = wsb + (size_t)ch * HWSZ + roff;
    float4 v;
    if (ldok) v = *(const float4*)(p + col0);
    else v = make_float4(0.f, 0.f, 0.f, 0.f);
    const float s1 = v.x + v.y, s2 = s1 + v.z, ts = s2 + v.w;
    const float incl = wave_incl_scan(ts);
    const float base = incl - ts;
    const float P0 = base + v.x, P1 = base + s1, P2 = base + s2, P3 = incl;
    const float PW = __shfl(P3, min(relmax >> 2, 63));
    const float hh[4] = {__shfl(P0, lane + 5), __shfl(P1, lane + 5),
                         __shfl(P2, lane + 5), __shfl(P3, lane + 5)};
    const float ll[4] = {P3, __shfl(P0, lane + 1), __shfl(P1, lane + 1),
                         __shfl(P2, lane + 1)};
    const int r0 = 4 * lane + 12;
#pragma unroll
    for (int j = 0; j < 4; ++j) {
      const float hi = (r0 + j + 8 <= relmax) ? hh[j] : PW;
      const float lo = (E + r0 + j >= 9) ? ll[j] : 0.f;
      out[j] = hi - lo;
    }
  };

  // guide means
  float mI[3][4];
#pragma unroll
  for (int k = 0; k < 3; ++k) {
    float t[4];
    hboxA(k, t);
#pragma unroll
    for (int j = 0; j < 4; ++j) mI[k][j] = t[j] * invN[j];
  }
  // covariance of guide -> inverse (symmetric 3x3)
  float inv[6][4];
  {
    float v19[4], v20[4], v21[4], v22[4], v23[4], v24[4];
    hboxA(19, v19); hboxA(20, v20); hboxA(21, v21);
    hboxA(22, v22); hboxA(23, v23); hboxA(24, v24);
#pragma unroll
    for (int j = 0; j < 4; ++j) {
      const float rr = v19[j] * invN[j] - mI[0][j] * mI[0][j] + EPSF;
      const float rg = v20[j] * invN[j] - mI[0][j] * mI[1][j];
      const float rb = v21[j] * invN[j] - mI[0][j] * mI[2][j];
      const float gg = v22[j] * invN[j] - mI[1][j] * mI[1][j] + EPSF;
      const float gb = v23[j] * invN[j] - mI[1][j] * mI[2][j];
      const float bb = v24[j] * invN[j] - mI[2][j] * mI[2][j] + EPSF;
      const float det = rr * gg * bb + 2.f * rg * gb * rb
                      - rb * gg * rb - rg * rg * bb - rr * gb * gb;
      const float idet = 1.0f / det;
      inv[0][j] = (gg * bb - gb * gb) * idet;
      inv[1][j] = (rb * gb - rg * bb) * idet;
      inv[2][j] = (rg * gb - rb * gg) * idet;
      inv[3][j] = (rr * bb - rb * rb) * idet;
      inv[4][j] = (rb * rg - rr * gb) * idet;
      inv[5][j] = (rr * gg - rg * rg) * idet;
    }
  }
  // per-src-channel solve -> a0,a1,a2,b
  float ab[16][4];
#pragma unroll
  for (int cc = 0; cc < 4; ++cc) {
    float mp[4], q0[4], q1[4], q2[4];
    hboxA(3 + cc, mp);
    hboxA(7 + cc, q0);
    hboxA(11 + cc, q1);
    hboxA(15 + cc, q2);
#pragma unroll
    for (int j = 0; j < 4; ++j) {
      const float m = mp[j] * invN[j];
      const float c0v = q0[j] * invN[j] - mI[0][j] * m;
      const float c1v = q1[j] * invN[j] - mI[1][j] * m;
      const float c2v = q2[j] * invN[j] - mI[2][j] * m;
      const float a0 = c0v * inv[0][j] + c1v * inv[1][j] + c2v * inv[2][j];
      const float a1 = c0v * inv[1][j] + c1v * inv[3][j] + c2v * inv[4][j];
      const float a2 = c0v * inv[2][j] + c1v * inv[4][j] + c2v * inv[5][j];
      const float bv = m - (a0 * mI[0][j] + a1 * mI[1][j] + a2 * mI[2][j]);
      ab[cc][j]      = abok ? a0 : 0.f;
      ab[4 + cc][j]  = abok ? a1 : 0.f;
      ab[8 + cc][j]  = abok ? a2 : 0.f;
      ab[12 + cc][j] = abok ? bv : 0.f;
    }
  }
  // phase B: hbox over a/b straight from registers -> planes 25..40
  const int qmax = relmax - 12;
  const int nstore = min(54, (WW - F) >> 2);
  const bool stok = lane < nstore;
  const size_t obase = roff + F + 4 * lane;
#pragma unroll
  for (int m = 0; m < 16; ++m) {
    const float x0 = ab[m][0], x1 = ab[m][1], x2 = ab[m][2], x3 = ab[m][3];
    const float s1 = x0 + x1, s2 = s1 + x2, ts = s2 + x3;
    const float incl = wave_incl_scan(ts);
    const float base = incl - ts;
    const float Q0 = base + x0, Q1 = base + s1, Q2 = base + s2, Q3 = incl;
    const float PW2 = __shfl(Q3, min(qmax >> 2, 63));
    const float hh[4] = {__shfl(Q0, lane + 4), __shfl(Q1, lane + 4),
                         __shfl(Q2, lane + 4), __shfl(Q3, lane + 4)};
    const float lm1 = __shfl(Q3, lane - 1);
    const float ll[4] = {lm1, Q0, Q1, Q2};
    const int qf0 = 8 + 4 * lane;
    float o[4];
#pragma unroll
    for (int j = 0; j < 4; ++j) {
      const float hi = (qf0 + j + 8 <= qmax) ? hh[j] : PW2;
      const float lo = (qf0 + j >= 9) ? ll[j] : 0.f;
      o[j] = hi - lo;
    }
    if (stok)
      *(float4*)(wsb + (size_t)(25 + m) * HWSZ + obase) =
          make_float4(o[0], o[1], o[2], o[3]);
  }
}

// ---------------- K3: vertical box of boxed a/b + combine with guide -> q
__global__ __launch_bounds__(64) void k_vbox_comb(const float* __restrict__ ws_,
                                                  const float* __restrict__ g,
                                                  float* __restrict__ out, int b0) {
  const int c0 = blockIdx.x * 128 + threadIdx.x * 2;
  const int y0 = blockIdx.y * V3R;
  const int b = b0 + blockIdx.z;
  const float* wsb = ws_ + (size_t)blockIdx.z * NPL * HWSZ + (size_t)25 * HWSZ;
  const float* gp0 = g + (size_t)(b * 3 + 0) * HWSZ;
  const float* gp1 = g + (size_t)(b * 3 + 1) * HWSZ;
  const float* gp2 = g + (size_t)(b * 3 + 2) * HWSZ;
  float* op0 = out + (size_t)(b * 4 + 0) * HWSZ;
  float* op1 = out + (size_t)(b * 4 + 1) * HWSZ;
  float* op2 = out + (size_t)(b * 4 + 2) * HWSZ;
  float* op3 = out + (size_t)(b * 4 + 3) * HWSZ;

  float acc[16][2];
#pragma unroll
  for (int i = 0; i < 16; ++i) { acc[i][0] = 0.f; acc[i][1] = 0.f; }

  auto row_op = [&](int y, bool add) {
    const int off = y * WW + c0;
#pragma unroll
    for (int i = 0; i < 16; ++i) {
      const float2 v = *(const float2*)(wsb + (size_t)i * HWSZ + off);
      if (add) { acc[i][0] += v.x; acc[i][1] += v.y; }
      else     { acc[i][0] -= v.x; acc[i][1] -= v.y; }
    }
  };

  for (int yy = y0 - RAD; yy <= y0 + RAD; ++yy)
    if (yy >= 0 && yy < HH) row_op(yy, true);

  float invnx[2];
#pragma unroll
  for (int k = 0; k < 2; ++k) {
    const int c = c0 + k;
    const int nx = min(c + RAD, WW - 1) - max(c - RAD, 0) + 1;
    invnx[k] = 1.0f / (float)nx;
  }

  for (int y = y0; y < y0 + V3R; ++y) {
    const int ny = min(y + RAD, HH - 1) - max(y - RAD, 0) + 1;
    const float invny = 1.0f / (float)ny;
    const size_t off = (size_t)y * WW + c0;
    const float2 G0 = *(const float2*)(gp0 + off);
    const float2 G1 = *(const float2*)(gp1 + off);
    const float2 G2 = *(const float2*)(gp2 + off);
    const float gk0[2] = {G0.x, G0.y}, gk1[2] = {G1.x, G1.y}, gk2[2] = {G2.x, G2.y};
    float o0[2], o1[2], o2[2], o3[2];
#pragma unroll
    for (int k = 0; k < 2; ++k) {
      const float invN = invnx[k] * invny;
      o0[k] = (acc[0][k] * gk0[k] + acc[4][k] * gk1[k] + acc[8][k]  * gk2[k] + acc[12][k]) * invN;
      o1[k] = (acc[1][k] * gk0[k] + acc[5][k] * gk1[k] + acc[9][k]  * gk2[k] + acc[13][k]) * invN;
      o2[k] = (acc[2][k] * gk0[k] + acc[6][k] * gk1[k] + acc[10][k] * gk2[k] + acc[14][k]) * invN;
      o3[k] = (acc[3][k] * gk0[k] + acc[7][k] * gk1[k] + acc[11][k] * gk2[k] + acc[15][k]) * invN;
    }
    *(float2*)(op0 + off) = make_float2(o0[0], o0[1]);
    *(float2*)(op1 + off) = make_float2(o1[0], o1[1]);
    *(float2*)(op2 + off) = make_float2(o2[0], o2[1]);
    *(float2*)(op3 + off) = make_float2(o3[0], o3[1]);
    const int ye = y + RAD + 1;
    if (ye < HH) row_op(ye, true);
    const int yl = y - RAD;
    if (yl >= 0) row_op(yl, false);
  }
}

extern "C" void kernel_launch(void* const* d_in, const int* in_sizes, int n_in,
                              void* d_out, int out_size, void* d_ws, size_t ws_size,
                              hipStream_t stream) {
  const float* x = (const float*)d_in[0];   // (4,4,1024,1024) src p
  const float* g = (const float*)d_in[1];   // (4,3,1024,1024) guide
  float* out = (float*)d_out;
  float* ws = (float*)d_ws;
  const size_t perBatchBytes = (size_t)NPL * HWSZ * sizeof(float);  // 172 MB
  int nb = (int)(ws_size / perBatchBytes);
  if (nb < 1) nb = 1;
  if (nb > 4) nb = 4;
  for (int b0 = 0; b0 < 4; b0 += nb) {
    const int nbc = (4 - b0 < nb) ? (4 - b0) : nb;
    dim3 g1(WW / 128, HH / V1R, nbc);
    dim3 g2(HH * NTL / 4, nbc);
    dim3 g3(WW / 128, HH / V3R, nbc);
    hipLaunchKernelGGL(k_vbox25, g1, dim3(64), 0, stream, x, g, ws, b0);
    hipLaunchKernelGGL(k_hbox_solve, g2, dim3(256), 0, stream, ws);
    hipLaunchKernelGGL(k_vbox_comb, g3, dim3(64), 0, stream, ws, g, out, b0);
  }
}